// Round 1
// 187.074 us; speedup vs baseline: 1.0267x; 1.0267x over previous
//
#include <hip/hip_runtime.h>

// Problem: B=32, GS=1024, PARAM=64, KEEPCONST=16, ITERATIONS=10, K_DIV=16.
// All tensors FLOAT32. Closed form of the 10-iteration recurrence:
//   out[row, j] = f^q(val[row, j&15]),  q = j>>4,  f(x) = clip(x*s, -1, 1),
//   s = sum(mat[row, :]) / 16.
// (q <= 3 <= ITERATIONS and cols 0..15 are pinned constants, so only the
// number of clip applications differs per 16-column group.)
//
// Structure: one wave owns ROWS_PER_WAVE=4 consecutive rows.
//  - 16 independent non-temporal dwordx4 loads in flight per lane (256 B/lane)
//  - 4 interleaved 6-step butterfly reduces (independent -> good ILP)
//  - epilogue: lane j emits column j for each of the 4 rows.
// Grid: 32768 rows / (4 waves * 4 rows) = 2048 blocks = 8 blocks/CU of work.

typedef float f32x4 __attribute__((ext_vector_type(4)));

#define ROWS_PER_WAVE 4

__global__ __launch_bounds__(256) void gltrivmlp_kernel(
    const float* __restrict__ mat,   // [nrows, 1024] f32
    const float* __restrict__ val,   // [nrows, 64]   f32
    float* __restrict__ out,         // [nrows, 64]   f32
    int nrows)
{
    const int gwave = (int)((blockIdx.x * (unsigned)blockDim.x + threadIdx.x) >> 6);
    const int lane  = (int)(threadIdx.x & 63u);
    const int row0  = gwave * ROWS_PER_WAVE;
    if (row0 >= nrows) return;

    // ---- issue all 16 loads up front: 4 rows x 4 contiguous 1 KiB segments ----
    f32x4 v[ROWS_PER_WAVE][4];
#pragma unroll
    for (int r = 0; r < ROWS_PER_WAVE; ++r) {
        const float* rowp = mat + (size_t)(row0 + r) * 1024 + lane * 4;
#pragma unroll
        for (int h = 0; h < 4; ++h) {
            // wave reads a contiguous 1 KiB segment: lane i -> floats [h*256+i*4, +4)
            v[r][h] = __builtin_nontemporal_load(
                (const f32x4*)(rowp + h * 256));
        }
    }

    // ---- per-row partial sums (independent chains) ----
    float sum[ROWS_PER_WAVE];
#pragma unroll
    for (int r = 0; r < ROWS_PER_WAVE; ++r) {
        float a = (v[r][0].x + v[r][0].y) + (v[r][0].z + v[r][0].w);
        float b = (v[r][1].x + v[r][1].y) + (v[r][1].z + v[r][1].w);
        float c = (v[r][2].x + v[r][2].y) + (v[r][2].z + v[r][2].w);
        float d = (v[r][3].x + v[r][3].y) + (v[r][3].z + v[r][3].w);
        sum[r] = (a + b) + (c + d);
    }

    // ---- 4 interleaved 64-lane butterfly reduces ----
#pragma unroll
    for (int off = 32; off >= 1; off >>= 1) {
#pragma unroll
        for (int r = 0; r < ROWS_PER_WAVE; ++r)
            sum[r] += __shfl_xor(sum[r], off, 64);
    }

    // ---- epilogue: lane j emits output column j for each of the 4 rows ----
    const int q = lane >> 4;
#pragma unroll
    for (int r = 0; r < ROWS_PER_WAVE; ++r) {
        const int rowi = row0 + r;
        if (rowi >= nrows) break;
        const float s = sum[r] * (1.0f / 16.0f);
        float x = val[(size_t)rowi * 64 + (lane & 15)];  // cols 0..15 broadcast
        if (q >= 1) x = fminf(fmaxf(x * s, -1.f), 1.f);
        if (q >= 2) x = fminf(fmaxf(x * s, -1.f), 1.f);
        if (q >= 3) x = fminf(fmaxf(x * s, -1.f), 1.f);
        __builtin_nontemporal_store(x, out + (size_t)rowi * 64 + lane);
    }
}

extern "C" void kernel_launch(void* const* d_in, const int* in_sizes, int n_in,
                              void* d_out, int out_size, void* d_ws, size_t ws_size,
                              hipStream_t stream) {
    (void)n_in; (void)d_ws; (void)ws_size; (void)out_size;
    const float* mat = (const float*)d_in[0];
    const float* val = (const float*)d_in[1];
    float* out = (float*)d_out;

    const int nrows = in_sizes[0] / 1024;                 // 32*1024 = 32768 rows
    const int rows_per_block = (256 / 64) * ROWS_PER_WAVE; // 16 rows / block
    const int grid = (nrows + rows_per_block - 1) / rows_per_block;

    gltrivmlp_kernel<<<grid, 256, 0, stream>>>(mat, val, out, nrows);
}

// Round 2
// 186.365 us; speedup vs baseline: 1.0306x; 1.0038x over previous
//
#include <hip/hip_runtime.h>

// Problem: B=32, GS=1024, PARAM=64, KEEPCONST=16, ITERATIONS=10, K_DIV=16.
// All tensors FLOAT32. Closed form of the 10-iteration recurrence:
//   out[row, j] = f^q(val[row, j&15]),  q = j>>4,  f(x) = clip(x*s, -1, 1),
//   s = sum(mat[row, :]) / 16.
// (q <= 3 <= ITERATIONS and cols 0..15 are pinned constants, so only the
// number of clip applications differs per 16-column group.)
//
// Structure: one wave owns ROWS_PER_WAVE=2 consecutive rows.
//  - 8 independent non-temporal dwordx4 loads in flight per lane (128 B/lane)
//    = 32 data VGPRs; __launch_bounds__(256, 8) pins total VGPR <= 64 so the
//    kernel sits below the 64-VGPR occupancy step -> 32 waves/CU resident
//    (vs 16 at ROWS=4). Same aggregate bytes in flight (256 KiB/CU), twice
//    the TLP to smooth over each wave's dependent reduce+store tail.
//  - 2 interleaved 6-step butterfly reduces
//  - epilogue: lane j emits column j for each of the 2 rows.
// Grid: 32768 rows / (4 waves * 2 rows) = 4096 blocks.

typedef float f32x4 __attribute__((ext_vector_type(4)));

#define ROWS_PER_WAVE 2

__global__ __launch_bounds__(256, 8) void gltrivmlp_kernel(
    const float* __restrict__ mat,   // [nrows, 1024] f32
    const float* __restrict__ val,   // [nrows, 64]   f32
    float* __restrict__ out,         // [nrows, 64]   f32
    int nrows)
{
    const int gwave = (int)((blockIdx.x * (unsigned)blockDim.x + threadIdx.x) >> 6);
    const int lane  = (int)(threadIdx.x & 63u);
    const int row0  = gwave * ROWS_PER_WAVE;
    if (row0 >= nrows) return;

    // ---- issue all 8 loads up front: 2 rows x 4 contiguous 1 KiB segments ----
    f32x4 v[ROWS_PER_WAVE][4];
#pragma unroll
    for (int r = 0; r < ROWS_PER_WAVE; ++r) {
        const float* rowp = mat + (size_t)(row0 + r) * 1024 + lane * 4;
#pragma unroll
        for (int h = 0; h < 4; ++h) {
            // wave reads a contiguous 1 KiB segment: lane i -> floats [h*256+i*4, +4)
            v[r][h] = __builtin_nontemporal_load(
                (const f32x4*)(rowp + h * 256));
        }
    }

    // ---- per-row partial sums (independent chains) ----
    float sum[ROWS_PER_WAVE];
#pragma unroll
    for (int r = 0; r < ROWS_PER_WAVE; ++r) {
        float a = (v[r][0].x + v[r][0].y) + (v[r][0].z + v[r][0].w);
        float b = (v[r][1].x + v[r][1].y) + (v[r][1].z + v[r][1].w);
        float c = (v[r][2].x + v[r][2].y) + (v[r][2].z + v[r][2].w);
        float d = (v[r][3].x + v[r][3].y) + (v[r][3].z + v[r][3].w);
        sum[r] = (a + b) + (c + d);
    }

    // ---- 2 interleaved 64-lane butterfly reduces ----
#pragma unroll
    for (int off = 32; off >= 1; off >>= 1) {
#pragma unroll
        for (int r = 0; r < ROWS_PER_WAVE; ++r)
            sum[r] += __shfl_xor(sum[r], off, 64);
    }

    // ---- epilogue: lane j emits output column j for each of the 2 rows ----
    const int q = lane >> 4;
#pragma unroll
    for (int r = 0; r < ROWS_PER_WAVE; ++r) {
        const int rowi = row0 + r;
        if (rowi >= nrows) break;
        const float s = sum[r] * (1.0f / 16.0f);
        float x = val[(size_t)rowi * 64 + (lane & 15)];  // cols 0..15 broadcast
        if (q >= 1) x = fminf(fmaxf(x * s, -1.f), 1.f);
        if (q >= 2) x = fminf(fmaxf(x * s, -1.f), 1.f);
        if (q >= 3) x = fminf(fmaxf(x * s, -1.f), 1.f);
        __builtin_nontemporal_store(x, out + (size_t)rowi * 64 + lane);
    }
}

extern "C" void kernel_launch(void* const* d_in, const int* in_sizes, int n_in,
                              void* d_out, int out_size, void* d_ws, size_t ws_size,
                              hipStream_t stream) {
    (void)n_in; (void)d_ws; (void)ws_size; (void)out_size;
    const float* mat = (const float*)d_in[0];
    const float* val = (const float*)d_in[1];
    float* out = (float*)d_out;

    const int nrows = in_sizes[0] / 1024;                  // 32*1024 = 32768 rows
    const int rows_per_block = (256 / 64) * ROWS_PER_WAVE; // 8 rows / block
    const int grid = (nrows + rows_per_block - 1) / rows_per_block;

    gltrivmlp_kernel<<<grid, 256, 0, stream>>>(mat, val, out, nrows);
}